// Round 1
// 362.870 us; speedup vs baseline: 1.0870x; 1.0870x over previous
//
#include <hip/hip_runtime.h>
#include <hip/hip_fp16.h>

#define NN 100000
#define NE 1600000
#define W_BKT 128
#define NB_BKT ((NN + W_BKT - 1) / W_BKT)   // 782
#define TILE_E 16384                         // edges per counting-sort tile
#define NT ((NE + TILE_E - 1) / TILE_E)      // 98
#define STAGE_CAP 4352                       // LDS staging (avg bucket ~2048)
// IN=128, HID=64, OUT=32

typedef _Float16 half2v __attribute__((ext_vector_type(2)));
typedef _Float16 half8v __attribute__((ext_vector_type(8)));
typedef float float2v __attribute__((ext_vector_type(2)));
typedef float float4v __attribute__((ext_vector_type(4)));

// ---- deterministic two-pass bucket sort + fused CSR/deg build (NO global atomics) ----

__global__ __launch_bounds__(256) void k_cnt(const int* __restrict__ dst,
                                             int* __restrict__ counts) {
    __shared__ int hc[NB_BKT];
    int tid = threadIdx.x;
    for (int i = tid; i < NB_BKT; i += 256) hc[i] = 0;
    __syncthreads();
    int base = blockIdx.x * TILE_E;
    int lim = base + TILE_E; if (lim > NE) lim = NE;
    for (int e = base + tid; e < lim; e += 256)
        atomicAdd(&hc[dst[e] >> 7], 1);
    __syncthreads();
    for (int i = tid; i < NB_BKT; i += 256)
        counts[blockIdx.x * NB_BKT + i] = hc[i];
}

__global__ __launch_bounds__(1024) void k_bscan(const int* __restrict__ counts,
                                                int* __restrict__ bucket_base) {
    __shared__ int buf[1024];
    int tid = threadIdx.x;
    int total = 0;
    if (tid < NB_BKT)
        for (int t = 0; t < NT; ++t) total += counts[t * NB_BKT + tid];
    buf[tid] = total;
    __syncthreads();
    for (int off = 1; off < 1024; off <<= 1) {
        int v = (tid >= off) ? buf[tid - off] : 0;
        __syncthreads();
        buf[tid] += v;
        __syncthreads();
    }
    if (tid < NB_BKT) bucket_base[tid] = buf[tid] - total;   // exclusive
    if (tid == 0) bucket_base[NB_BKT] = NE;
}

__global__ __launch_bounds__(256) void k_offs(const int* __restrict__ bucket_base,
                                              int* __restrict__ counts) {
    int b = blockIdx.x * 256 + threadIdx.x;
    if (b >= NB_BKT) return;
    int off = bucket_base[b];
    for (int t = 0; t < NT; ++t) {
        int c = counts[t * NB_BKT + b];
        counts[t * NB_BKT + b] = off;
        off += c;
    }
}

__global__ __launch_bounds__(256) void k_place(const int* __restrict__ src,
                                               const int* __restrict__ dst,
                                               const int* __restrict__ counts,
                                               int* __restrict__ ebuf) {
    __shared__ int cur[NB_BKT];
    int tid = threadIdx.x;
    for (int i = tid; i < NB_BKT; i += 256)
        cur[i] = counts[blockIdx.x * NB_BKT + i];
    __syncthreads();
    int base = blockIdx.x * TILE_E;
    int lim = base + TILE_E; if (lim > NE) lim = NE;
    for (int e = base + tid; e < lim; e += 256) {
        int s = src[e], d = dst[e];
        int pos = atomicAdd(&cur[d >> 7], 1);     // LDS atomic, ~21/counter
        ebuf[pos] = (s << 7) | (d & 127);
    }
}

// one block per bucket: LDS-stage the bucket's ebuf slice, count 128 node degs,
// prefix-scan -> row_ptr + dis, then scatter to csr_src.
__global__ __launch_bounds__(256) void k_build(const int* __restrict__ bucket_base,
                                               const int* __restrict__ ebuf,
                                               int* __restrict__ csr_src,
                                               int* __restrict__ row_ptr,
                                               float* __restrict__ dis) {
    __shared__ int deg[W_BKT];
    __shared__ int pre[W_BKT];
    __shared__ int cur[W_BKT];
    __shared__ int stage[STAGE_CAP];
    int b = blockIdx.x;
    int tid = threadIdx.x;
    int beg = bucket_base[b], end = bucket_base[b + 1];
    int n = end - beg;
    if (tid < W_BKT) deg[tid] = 0;
    __syncthreads();
    bool fits = (n <= STAGE_CAP);
    if (fits) {
        for (int i = tid; i < n; i += 256) {
            int val = ebuf[beg + i];
            stage[i] = val;
            atomicAdd(&deg[val & 127], 1);
        }
    } else {
        for (int i = tid; i < n; i += 256)
            atomicAdd(&deg[ebuf[beg + i] & 127], 1);
    }
    __syncthreads();
    if (tid < W_BKT) pre[tid] = deg[tid];
    __syncthreads();
    for (int off = 1; off < W_BKT; off <<= 1) {
        int v = (tid >= off && tid < W_BKT) ? pre[tid - off] : 0;
        __syncthreads();
        if (tid < W_BKT) pre[tid] += v;
        __syncthreads();
    }
    if (tid < W_BKT) {
        int v = b * W_BKT + tid;
        int rp = beg + pre[tid] - deg[tid];      // exclusive prefix
        if (v < NN) {
            row_ptr[v] = rp;
            dis[v] = rsqrtf((float)(1 + deg[tid]));
        }
        cur[tid] = rp;
    }
    if (b == NB_BKT - 1 && tid == 0) row_ptr[NN] = NE;
    __syncthreads();
    if (fits) {
        for (int i = tid; i < n; i += 256) {
            int val = stage[i];
            int pos = atomicAdd(&cur[val & 127], 1);
            csr_src[pos] = val >> 7;
        }
    } else {
        for (int i = tid; i < n; i += 256) {
            int val = ebuf[beg + i];
            int pos = atomicAdd(&cur[val & 127], 1);
            csr_src[pos] = val >> 7;
        }
    }
}

// ---------------- dense transforms via MFMA (dis folded into stored rows) ----------------
// W pre-packed into fragment-ordered f16 hi/lo tables (split: w = hi + lo, lo captures
// the fp16 rounding residual). GEMM computes Ah*Bh + Al*Bh + Ah*Bl -> fp32-equivalent.

__global__ __launch_bounds__(256) void k_wprep(const float* __restrict__ W1,
                                               const float* __restrict__ Wmu,
                                               const float* __restrict__ Wls,
                                               _Float16* __restrict__ wf1h,
                                               _Float16* __restrict__ wf1l,
                                               _Float16* __restrict__ wf2h,
                                               _Float16* __restrict__ wf2l) {
    int tid = threadIdx.x;
    // gemm1 fragments: frag f = (ct*4 + kc)*64 + lane, 8 consecutive k per lane
    for (int f = tid; f < 4 * 4 * 64; f += 256) {
        int lane = f & 63;
        int kc = (f >> 6) & 3;
        int ct = f >> 8;
        int col = ct * 16 + (lane & 15);
        int k0 = kc * 32 + (lane >> 4) * 8;
#pragma unroll
        for (int j = 0; j < 8; ++j) {
            float w = W1[(k0 + j) * 64 + col];
            _Float16 hi = (_Float16)w;
            wf1h[f * 8 + j] = hi;
            wf1l[f * 8 + j] = (_Float16)(w - (float)hi);
        }
    }
    // gemm2 fragments: frag f = (ct*2 + kc)*64 + lane; cols = [Wmu | Wls]
    for (int f = tid; f < 4 * 2 * 64; f += 256) {
        int lane = f & 63;
        int kc = (f >> 6) & 1;
        int ct = f >> 7;
        int col = ct * 16 + (lane & 15);
        int k0 = kc * 32 + (lane >> 4) * 8;
#pragma unroll
        for (int j = 0; j < 8; ++j) {
            int k = k0 + j;
            float w = (col < 32) ? Wmu[k * 32 + col] : Wls[k * 32 + (col - 32)];
            _Float16 hi = (_Float16)w;
            wf2h[f * 8 + j] = hi;
            wf2l[f * 8 + j] = (_Float16)(w - (float)hi);
        }
    }
}

__device__ __forceinline__ void split8(const float4 a, const float4 b,
                                       half8v& hi, half8v& lo) {
    float v[8] = {a.x, a.y, a.z, a.w, b.x, b.y, b.z, b.w};
#pragma unroll
    for (int i = 0; i < 8; ++i) {
        _Float16 h = (_Float16)v[i];
        hi[i] = h;
        lo[i] = (_Float16)(v[i] - (float)h);
    }
}

// t1'[v] = dis[v] * (x[v] @ W1), stored fp16. 64 rows/block, 16 rows/wave, no LDS.
__global__ __launch_bounds__(256) void k_gemm1(const float* __restrict__ x,
                                               const _Float16* __restrict__ wf1h,
                                               const _Float16* __restrict__ wf1l,
                                               const float* __restrict__ dis,
                                               _Float16* __restrict__ t1) {
    int tid = threadIdx.x;
    int lane = tid & 63;
    int wv = tid >> 6;
    int wrow = blockIdx.x * 64 + wv * 16;
    int cl = lane & 15, kg = lane >> 4;
    const half8v* Bh = (const half8v*)wf1h;
    const half8v* Bl = (const half8v*)wf1l;
    float4v acc[4] = {};
    int r = wrow + cl;
    long rr = (r < NN) ? r : (NN - 1);
    const float4* xp = (const float4*)(x + rr * 128);
#pragma unroll
    for (int kc = 0; kc < 4; ++kc) {
        float4 xa = xp[kc * 8 + kg * 2];
        float4 xb = xp[kc * 8 + kg * 2 + 1];
        half8v ah, al;
        split8(xa, xb, ah, al);
#pragma unroll
        for (int ct = 0; ct < 4; ++ct) {
            half8v bh = Bh[(ct * 4 + kc) * 64 + lane];
            half8v bl = Bl[(ct * 4 + kc) * 64 + lane];
            acc[ct] = __builtin_amdgcn_mfma_f32_16x16x32_f16(ah, bh, acc[ct], 0, 0, 0);
            acc[ct] = __builtin_amdgcn_mfma_f32_16x16x32_f16(al, bh, acc[ct], 0, 0, 0);
            acc[ct] = __builtin_amdgcn_mfma_f32_16x16x32_f16(ah, bl, acc[ct], 0, 0, 0);
        }
    }
#pragma unroll
    for (int j = 0; j < 4; ++j) {
        int row = wrow + kg * 4 + j;
        if (row < NN) {
            float dv = dis[row];
#pragma unroll
            for (int ct = 0; ct < 4; ++ct)
                t1[(long)row * 64 + ct * 16 + cl] = (_Float16)(acc[ct][j] * dv);
        }
    }
}

// t2'[v] = dis[v] * (h[v] @ [Wmu | Wls]), stored fp16
__global__ __launch_bounds__(256) void k_gemm2(const float* __restrict__ h,
                                               const _Float16* __restrict__ wf2h,
                                               const _Float16* __restrict__ wf2l,
                                               const float* __restrict__ dis,
                                               _Float16* __restrict__ t2) {
    int tid = threadIdx.x;
    int lane = tid & 63;
    int wv = tid >> 6;
    int wrow = blockIdx.x * 64 + wv * 16;
    int cl = lane & 15, kg = lane >> 4;
    const half8v* Bh = (const half8v*)wf2h;
    const half8v* Bl = (const half8v*)wf2l;
    float4v acc[4] = {};
    int r = wrow + cl;
    long rr = (r < NN) ? r : (NN - 1);
    const float4* hp = (const float4*)(h + rr * 64);
#pragma unroll
    for (int kc = 0; kc < 2; ++kc) {
        float4 xa = hp[kc * 8 + kg * 2];
        float4 xb = hp[kc * 8 + kg * 2 + 1];
        half8v ah, al;
        split8(xa, xb, ah, al);
#pragma unroll
        for (int ct = 0; ct < 4; ++ct) {
            half8v bh = Bh[(ct * 2 + kc) * 64 + lane];
            half8v bl = Bl[(ct * 2 + kc) * 64 + lane];
            acc[ct] = __builtin_amdgcn_mfma_f32_16x16x32_f16(ah, bh, acc[ct], 0, 0, 0);
            acc[ct] = __builtin_amdgcn_mfma_f32_16x16x32_f16(al, bh, acc[ct], 0, 0, 0);
            acc[ct] = __builtin_amdgcn_mfma_f32_16x16x32_f16(ah, bl, acc[ct], 0, 0, 0);
        }
    }
#pragma unroll
    for (int j = 0; j < 4; ++j) {
        int row = wrow + kg * 4 + j;
        if (row < NN) {
            float dv = dis[row];
#pragma unroll
            for (int ct = 0; ct < 4; ++ct)
                t2[(long)row * 64 + ct * 16 + cl] = (_Float16)(acc[ct][j] * dv);
        }
    }
}

// ---------------- fused gather-aggregations ----------------
// Tables pre-scaled by dis[src]: inner loop = shfl -> load -> cvt+add only.
// 2 nodes per wave (32 lanes each); lane covers dims 2*j2, 2*j2+1 (fp16x2).

// h[v] = l2normalize(relu(dis[v]*(sum_s t1'[s] + t1'[v]) + b1))
__global__ __launch_bounds__(256) void k_agg1(const half2v* __restrict__ tv,
                                              const int* __restrict__ row_ptr,
                                              const int* __restrict__ csr_src,
                                              const float* __restrict__ dis,
                                              const float* __restrict__ b1,
                                              float* __restrict__ h) {
    int lane = threadIdx.x & 63;
    int j2 = lane & 31;
    int v = blockIdx.x * 8 + (threadIdx.x >> 6) * 2 + (lane >> 5);   // NN = 12500*8
    int beg = row_ptr[v], end = row_ptr[v + 1];
    float acc0 = 0.f, acc1 = 0.f;
    for (int base = beg; base < end; base += 32) {
        int cnt = end - base; if (cnt > 32) cnt = 32;
        int idx = 0;
        if (j2 < cnt) idx = csr_src[base + j2];
        int k = 0;
        for (; k + 8 <= cnt; k += 8) {
            int s0 = __shfl(idx, k, 32),     s1 = __shfl(idx, k + 1, 32),
                s2 = __shfl(idx, k + 2, 32), s3 = __shfl(idx, k + 3, 32),
                s4 = __shfl(idx, k + 4, 32), s5 = __shfl(idx, k + 5, 32),
                s6 = __shfl(idx, k + 6, 32), s7 = __shfl(idx, k + 7, 32);
            half2v r0 = tv[s0 * 32 + j2];
            half2v r1 = tv[s1 * 32 + j2];
            half2v r2 = tv[s2 * 32 + j2];
            half2v r3 = tv[s3 * 32 + j2];
            half2v r4 = tv[s4 * 32 + j2];
            half2v r5 = tv[s5 * 32 + j2];
            half2v r6 = tv[s6 * 32 + j2];
            half2v r7 = tv[s7 * 32 + j2];
            acc0 += (float)r0.x; acc1 += (float)r0.y;
            acc0 += (float)r1.x; acc1 += (float)r1.y;
            acc0 += (float)r2.x; acc1 += (float)r2.y;
            acc0 += (float)r3.x; acc1 += (float)r3.y;
            acc0 += (float)r4.x; acc1 += (float)r4.y;
            acc0 += (float)r5.x; acc1 += (float)r5.y;
            acc0 += (float)r6.x; acc1 += (float)r6.y;
            acc0 += (float)r7.x; acc1 += (float)r7.y;
        }
        for (; k < cnt; ++k) {
            int s = __shfl(idx, k, 32);
            half2v r = tv[s * 32 + j2];
            acc0 += (float)r.x; acc1 += (float)r.y;
        }
    }
    float dv = dis[v];
    half2v rv = tv[v * 32 + j2];                 // = dis[v]*t1[v]
    float val0 = dv * (acc0 + (float)rv.x) + b1[2 * j2];
    float val1 = dv * (acc1 + (float)rv.y) + b1[2 * j2 + 1];
    val0 = fmaxf(val0, 0.0f);
    val1 = fmaxf(val1, 0.0f);
    float ss = val0 * val0 + val1 * val1;
#pragma unroll
    for (int m = 1; m < 32; m <<= 1) ss += __shfl_xor(ss, m);
    float scale = 1.0f / fmaxf(sqrtf(ss), 1e-12f);
    float2v* h2 = (float2v*)h;
    float2v hv; hv.x = val0 * scale; hv.y = val1 * scale;
    h2[v * 32 + j2] = hv;
}

// layer-2 aggregation fused with bias + reparametrize; writes mu, ls (f32), z (fp16)
__global__ __launch_bounds__(256) void k_agg2(const half2v* __restrict__ tv,
                                              const int* __restrict__ row_ptr,
                                              const int* __restrict__ csr_src,
                                              const float* __restrict__ dis,
                                              const float* __restrict__ bmu,
                                              const float* __restrict__ bls,
                                              const float* __restrict__ eps,
                                              float* __restrict__ mu,
                                              float* __restrict__ ls,
                                              _Float16* __restrict__ zh) {
    int lane = threadIdx.x & 63;
    int j2 = lane & 31;
    int v = blockIdx.x * 8 + (threadIdx.x >> 6) * 2 + (lane >> 5);
    int beg = row_ptr[v], end = row_ptr[v + 1];
    float acc0 = 0.f, acc1 = 0.f;
    for (int base = beg; base < end; base += 32) {
        int cnt = end - base; if (cnt > 32) cnt = 32;
        int idx = 0;
        if (j2 < cnt) idx = csr_src[base + j2];
        int k = 0;
        for (; k + 8 <= cnt; k += 8) {
            int s0 = __shfl(idx, k, 32),     s1 = __shfl(idx, k + 1, 32),
                s2 = __shfl(idx, k + 2, 32), s3 = __shfl(idx, k + 3, 32),
                s4 = __shfl(idx, k + 4, 32), s5 = __shfl(idx, k + 5, 32),
                s6 = __shfl(idx, k + 6, 32), s7 = __shfl(idx, k + 7, 32);
            half2v r0 = tv[s0 * 32 + j2];
            half2v r1 = tv[s1 * 32 + j2];
            half2v r2 = tv[s2 * 32 + j2];
            half2v r3 = tv[s3 * 32 + j2];
            half2v r4 = tv[s4 * 32 + j2];
            half2v r5 = tv[s5 * 32 + j2];
            half2v r6 = tv[s6 * 32 + j2];
            half2v r7 = tv[s7 * 32 + j2];
            acc0 += (float)r0.x; acc1 += (float)r0.y;
            acc0 += (float)r1.x; acc1 += (float)r1.y;
            acc0 += (float)r2.x; acc1 += (float)r2.y;
            acc0 += (float)r3.x; acc1 += (float)r3.y;
            acc0 += (float)r4.x; acc1 += (float)r4.y;
            acc0 += (float)r5.x; acc1 += (float)r5.y;
            acc0 += (float)r6.x; acc1 += (float)r6.y;
            acc0 += (float)r7.x; acc1 += (float)r7.y;
        }
        for (; k < cnt; ++k) {
            int s = __shfl(idx, k, 32);
            half2v r = tv[s * 32 + j2];
            acc0 += (float)r.x; acc1 += (float)r.y;
        }
    }
    float dv = dis[v];
    half2v rv = tv[v * 32 + j2];                 // = dis[v]*t2[v]
    float bb0 = (j2 < 16) ? bmu[2 * j2]     : bls[2 * j2 - 32];
    float bb1 = (j2 < 16) ? bmu[2 * j2 + 1] : bls[2 * j2 - 31];
    float val0 = dv * (acc0 + (float)rv.x) + bb0;
    float val1 = dv * (acc1 + (float)rv.y) + bb1;
    float o0 = __shfl_xor(val0, 16);
    float o1 = __shfl_xor(val1, 16);
    float2v* mu2 = (float2v*)mu;
    float2v* ls2 = (float2v*)ls;
    half2v* z2  = (half2v*)zh;
    const float2* e2 = (const float2*)eps;
    if (j2 < 16) {
        float2v mv; mv.x = val0; mv.y = val1;
        __builtin_nontemporal_store(mv, &mu2[v * 16 + j2]);
        float2 ev = e2[v * 16 + j2];
        float l0 = fminf(fmaxf(o0, -10.0f), 10.0f);
        float l1 = fminf(fmaxf(o1, -10.0f), 10.0f);
        half2v zw;
        zw.x = (_Float16)(val0 + ev.x * expf(l0));
        zw.y = (_Float16)(val1 + ev.y * expf(l1));
        z2[v * 16 + j2] = zw;
    } else {
        float2v lv; lv.x = val0; lv.y = val1;
        __builtin_nontemporal_store(lv, &ls2[v * 16 + (j2 - 16)]);
    }
}

// adj_pred[e] = sigmoid(<z[src], z[dst]>); z fp16 (row = 64 B = 1 line),
// 4 lanes per edge, 16 B loads
__global__ __launch_bounds__(256) void k_decode(const _Float16* __restrict__ zh,
                                                const int* __restrict__ src,
                                                const int* __restrict__ dst,
                                                float* __restrict__ out) {
    long t = (long)blockIdx.x * 256 + threadIdx.x;
    long e = t >> 2; int l = (int)(t & 3);
    if (e >= NE) return;
    int s = src[e], d = dst[e];
    const half8v* z8 = (const half8v*)zh;
    half8v a = z8[s * 4 + l];
    half8v b = z8[d * 4 + l];
    float p = 0.f;
#pragma unroll
    for (int i = 0; i < 8; ++i) p += (float)a[i] * (float)b[i];
    p += __shfl_xor(p, 1);
    p += __shfl_xor(p, 2);
    if (l == 0) out[e] = 1.0f / (1.0f + expf(-p));
}

extern "C" void kernel_launch(void* const* d_in, const int* in_sizes, int n_in,
                              void* d_out, int out_size, void* d_ws, size_t ws_size,
                              hipStream_t stream) {
    const float* x   = (const float*)d_in[0];
    const int*   ei  = (const int*)d_in[1];
    const float* eps = (const float*)d_in[2];
    const float* W1  = (const float*)d_in[3];
    const float* b1  = (const float*)d_in[4];
    const float* Wmu = (const float*)d_in[5];
    const float* bmu = (const float*)d_in[6];
    const float* Wls = (const float*)d_in[7];
    const float* bls = (const float*)d_in[8];
    const int* src = ei;        // edge_index[0]
    const int* dst = ei + NE;   // edge_index[1]

    float* out = (float*)d_out;
    float* adj = out;                       // [E]
    float* mu  = out + NE;                  // [N,32]
    float* ls  = mu + (long)NN * 32;        // [N,32]

    // workspace layout (all block byte sizes multiples of 16; z 64B-aligned)
    float* dis      = (float*)d_ws;              // NN
    int*   row_ptr  = (int*)(dis + NN);          // 100004
    int*   bucket_base = row_ptr + 100004;       // NB_BKT+1 -> pad 784
    int*   counts   = bucket_base + 784;         // NT*NB_BKT = 76636 -> pad 76640
    int*   ebuf     = counts + 76640;            // NE
    int*   csr_src  = ebuf + NE;                 // NE
    _Float16* t     = (_Float16*)(csr_src + NE); // NN*64 fp16 (t1' then t2')
    float* h        = (float*)(t + (long)NN * 64);         // NN*64 f32
    _Float16* zh    = (_Float16*)(h + (long)NN * 64 + 12); // NN*32 fp16, 64B-aligned

    // W fragment tables alias the counts region (dead after k_place; k_wprep is
    // stream-ordered after k_place). 49152 B << 306 KB region, 16B-aligned.
    _Float16* wf1h = (_Float16*)counts;          // 16x64x8 = 8192 f16
    _Float16* wf1l = wf1h + 8192;                // 8192
    _Float16* wf2h = wf1l + 8192;                // 8x64x8 = 4096
    _Float16* wf2l = wf2h + 4096;                // 4096

    const int B = 256;

    // CSR + deg/dis build — zero global atomics
    k_cnt  <<<NT, B, 0, stream>>>(dst, counts);
    k_bscan<<<1, 1024, 0, stream>>>(counts, bucket_base);
    k_offs <<<(NB_BKT + B - 1) / B, B, 0, stream>>>(bucket_base, counts);
    k_place<<<NT, B, 0, stream>>>(src, dst, counts, ebuf);
    k_wprep<<<1, B, 0, stream>>>(W1, Wmu, Wls, wf1h, wf1l, wf2h, wf2l);
    k_build<<<NB_BKT, B, 0, stream>>>(bucket_base, ebuf, csr_src, row_ptr, dis);

    // layer 1
    k_gemm1<<<(NN + 63) / 64, B, 0, stream>>>(x, wf1h, wf1l, dis, t);
    k_agg1 <<<NN / 8, B, 0, stream>>>((const half2v*)t, row_ptr, csr_src, dis, b1, h);

    // layer 2
    k_gemm2<<<(NN + 63) / 64, B, 0, stream>>>(h, wf2h, wf2l, dis, t);
    k_agg2 <<<NN / 8, B, 0, stream>>>((const half2v*)t, row_ptr, csr_src, dis,
                                      bmu, bls, eps, mu, ls, zh);

    // decode
    k_decode<<<(int)(((long)NE * 4 + B - 1) / B), B, 0, stream>>>(zh, src, dst, adj);
}

// Round 4
// 346.412 us; speedup vs baseline: 1.1387x; 1.0475x over previous
//
#include <hip/hip_runtime.h>
#include <hip/hip_fp16.h>

#define NN 100000
#define NE 1600000
#define W_BKT 128
#define NB_BKT ((NN + W_BKT - 1) / W_BKT)   // 782
#define TILE_E 16384                         // edges per counting-sort tile
#define NT ((NE + TILE_E - 1) / TILE_E)      // 98
#define STAGE_CAP 4352                       // LDS staging (avg bucket ~2048)
// IN=128, HID=64, OUT=32

typedef _Float16 half2v __attribute__((ext_vector_type(2)));
typedef _Float16 half4v __attribute__((ext_vector_type(4)));
typedef _Float16 half8v __attribute__((ext_vector_type(8)));
typedef float float2v __attribute__((ext_vector_type(2)));
typedef float float4v __attribute__((ext_vector_type(4)));

// ---- deterministic two-pass bucket sort + fused CSR/deg build (NO global atomics) ----

__global__ __launch_bounds__(256) void k_cnt(const int* __restrict__ dst,
                                             int* __restrict__ counts) {
    __shared__ int hc[NB_BKT];
    int tid = threadIdx.x;
    for (int i = tid; i < NB_BKT; i += 256) hc[i] = 0;
    __syncthreads();
    int base = blockIdx.x * TILE_E;
    int lim = base + TILE_E; if (lim > NE) lim = NE;
    for (int e = base + tid; e < lim; e += 256)
        atomicAdd(&hc[dst[e] >> 7], 1);
    __syncthreads();
    for (int i = tid; i < NB_BKT; i += 256)
        counts[blockIdx.x * NB_BKT + i] = hc[i];
}

__global__ __launch_bounds__(1024) void k_bscan(const int* __restrict__ counts,
                                                int* __restrict__ bucket_base) {
    __shared__ int buf[1024];
    int tid = threadIdx.x;
    int total = 0;
    if (tid < NB_BKT)
        for (int t = 0; t < NT; ++t) total += counts[t * NB_BKT + tid];
    buf[tid] = total;
    __syncthreads();
    for (int off = 1; off < 1024; off <<= 1) {
        int v = (tid >= off) ? buf[tid - off] : 0;
        __syncthreads();
        buf[tid] += v;
        __syncthreads();
    }
    if (tid < NB_BKT) bucket_base[tid] = buf[tid] - total;   // exclusive
    if (tid == 0) bucket_base[NB_BKT] = NE;
}

__global__ __launch_bounds__(256) void k_offs(const int* __restrict__ bucket_base,
                                              int* __restrict__ counts) {
    int b = blockIdx.x * 256 + threadIdx.x;
    if (b >= NB_BKT) return;
    int off = bucket_base[b];
    for (int t = 0; t < NT; ++t) {
        int c = counts[t * NB_BKT + b];
        counts[t * NB_BKT + b] = off;
        off += c;
    }
}

__global__ __launch_bounds__(256) void k_place(const int* __restrict__ src,
                                               const int* __restrict__ dst,
                                               const int* __restrict__ counts,
                                               int* __restrict__ ebuf) {
    __shared__ int cur[NB_BKT];
    int tid = threadIdx.x;
    for (int i = tid; i < NB_BKT; i += 256)
        cur[i] = counts[blockIdx.x * NB_BKT + i];
    __syncthreads();
    int base = blockIdx.x * TILE_E;
    int lim = base + TILE_E; if (lim > NE) lim = NE;
    for (int e = base + tid; e < lim; e += 256) {
        int s = src[e], d = dst[e];
        int pos = atomicAdd(&cur[d >> 7], 1);     // LDS atomic, ~21/counter
        ebuf[pos] = (s << 7) | (d & 127);
    }
}

// one block per bucket: LDS-stage the bucket's ebuf slice, count 128 node degs,
// prefix-scan -> row_ptr + dis, then scatter to csr_src.
__global__ __launch_bounds__(256) void k_build(const int* __restrict__ bucket_base,
                                               const int* __restrict__ ebuf,
                                               int* __restrict__ csr_src,
                                               int* __restrict__ row_ptr,
                                               float* __restrict__ dis) {
    __shared__ int deg[W_BKT];
    __shared__ int pre[W_BKT];
    __shared__ int cur[W_BKT];
    __shared__ int stage[STAGE_CAP];
    int b = blockIdx.x;
    int tid = threadIdx.x;
    int beg = bucket_base[b], end = bucket_base[b + 1];
    int n = end - beg;
    if (tid < W_BKT) deg[tid] = 0;
    __syncthreads();
    bool fits = (n <= STAGE_CAP);
    if (fits) {
        for (int i = tid; i < n; i += 256) {
            int val = ebuf[beg + i];
            stage[i] = val;
            atomicAdd(&deg[val & 127], 1);
        }
    } else {
        for (int i = tid; i < n; i += 256)
            atomicAdd(&deg[ebuf[beg + i] & 127], 1);
    }
    __syncthreads();
    if (tid < W_BKT) pre[tid] = deg[tid];
    __syncthreads();
    for (int off = 1; off < W_BKT; off <<= 1) {
        int v = (tid >= off && tid < W_BKT) ? pre[tid - off] : 0;
        __syncthreads();
        if (tid < W_BKT) pre[tid] += v;
        __syncthreads();
    }
    if (tid < W_BKT) {
        int v = b * W_BKT + tid;
        int rp = beg + pre[tid] - deg[tid];      // exclusive prefix
        if (v < NN) {
            row_ptr[v] = rp;
            dis[v] = rsqrtf((float)(1 + deg[tid]));
        }
        cur[tid] = rp;
    }
    if (b == NB_BKT - 1 && tid == 0) row_ptr[NN] = NE;
    __syncthreads();
    if (fits) {
        for (int i = tid; i < n; i += 256) {
            int val = stage[i];
            int pos = atomicAdd(&cur[val & 127], 1);
            csr_src[pos] = val >> 7;
        }
    } else {
        for (int i = tid; i < n; i += 256) {
            int val = ebuf[beg + i];
            int pos = atomicAdd(&cur[val & 127], 1);
            csr_src[pos] = val >> 7;
        }
    }
}

// ---------------- dense transforms via MFMA (dis folded into stored rows) ----------------
// W pre-packed into fragment-ordered f16 hi/lo tables (split: w = hi + lo, lo captures
// the fp16 rounding residual). GEMM computes Ah*Bh + Al*Bh + Ah*Bl -> fp32-equivalent.

__global__ __launch_bounds__(256) void k_wprep(const float* __restrict__ W1,
                                               const float* __restrict__ Wmu,
                                               const float* __restrict__ Wls,
                                               _Float16* __restrict__ wf1h,
                                               _Float16* __restrict__ wf1l,
                                               _Float16* __restrict__ wf2h,
                                               _Float16* __restrict__ wf2l) {
    int tid = threadIdx.x;
    // gemm1 fragments: frag f = (ct*4 + kc)*64 + lane, 8 consecutive k per lane
    for (int f = tid; f < 4 * 4 * 64; f += 256) {
        int lane = f & 63;
        int kc = (f >> 6) & 3;
        int ct = f >> 8;
        int col = ct * 16 + (lane & 15);
        int k0 = kc * 32 + (lane >> 4) * 8;
#pragma unroll
        for (int j = 0; j < 8; ++j) {
            float w = W1[(k0 + j) * 64 + col];
            _Float16 hi = (_Float16)w;
            wf1h[f * 8 + j] = hi;
            wf1l[f * 8 + j] = (_Float16)(w - (float)hi);
        }
    }
    // gemm2 fragments: frag f = (ct*2 + kc)*64 + lane; cols = [Wmu | Wls]
    for (int f = tid; f < 4 * 2 * 64; f += 256) {
        int lane = f & 63;
        int kc = (f >> 6) & 1;
        int ct = f >> 7;
        int col = ct * 16 + (lane & 15);
        int k0 = kc * 32 + (lane >> 4) * 8;
#pragma unroll
        for (int j = 0; j < 8; ++j) {
            int k = k0 + j;
            float w = (col < 32) ? Wmu[k * 32 + col] : Wls[k * 32 + (col - 32)];
            _Float16 hi = (_Float16)w;
            wf2h[f * 8 + j] = hi;
            wf2l[f * 8 + j] = (_Float16)(w - (float)hi);
        }
    }
}

__device__ __forceinline__ void split8(const float4 a, const float4 b,
                                       half8v& hi, half8v& lo) {
    float v[8] = {a.x, a.y, a.z, a.w, b.x, b.y, b.z, b.w};
#pragma unroll
    for (int i = 0; i < 8; ++i) {
        _Float16 h = (_Float16)v[i];
        hi[i] = h;
        lo[i] = (_Float16)(v[i] - (float)h);
    }
}

// t1'[v] = dis[v] * (x[v] @ W1), stored fp16. 64 rows/block, 16 rows/wave, no LDS.
__global__ __launch_bounds__(256) void k_gemm1(const float* __restrict__ x,
                                               const _Float16* __restrict__ wf1h,
                                               const _Float16* __restrict__ wf1l,
                                               const float* __restrict__ dis,
                                               _Float16* __restrict__ t1) {
    int tid = threadIdx.x;
    int lane = tid & 63;
    int wv = tid >> 6;
    int wrow = blockIdx.x * 64 + wv * 16;
    int cl = lane & 15, kg = lane >> 4;
    const half8v* Bh = (const half8v*)wf1h;
    const half8v* Bl = (const half8v*)wf1l;
    float4v acc[4] = {};
    int r = wrow + cl;
    long rr = (r < NN) ? r : (NN - 1);
    const float4* xp = (const float4*)(x + rr * 128);
#pragma unroll
    for (int kc = 0; kc < 4; ++kc) {
        float4 xa = xp[kc * 8 + kg * 2];
        float4 xb = xp[kc * 8 + kg * 2 + 1];
        half8v ah, al;
        split8(xa, xb, ah, al);
#pragma unroll
        for (int ct = 0; ct < 4; ++ct) {
            half8v bh = Bh[(ct * 4 + kc) * 64 + lane];
            half8v bl = Bl[(ct * 4 + kc) * 64 + lane];
            acc[ct] = __builtin_amdgcn_mfma_f32_16x16x32_f16(ah, bh, acc[ct], 0, 0, 0);
            acc[ct] = __builtin_amdgcn_mfma_f32_16x16x32_f16(al, bh, acc[ct], 0, 0, 0);
            acc[ct] = __builtin_amdgcn_mfma_f32_16x16x32_f16(ah, bl, acc[ct], 0, 0, 0);
        }
    }
#pragma unroll
    for (int j = 0; j < 4; ++j) {
        int row = wrow + kg * 4 + j;
        if (row < NN) {
            float dv = dis[row];
#pragma unroll
            for (int ct = 0; ct < 4; ++ct)
                t1[(long)row * 64 + ct * 16 + cl] = (_Float16)(acc[ct][j] * dv);
        }
    }
}

// t2'[v] = dis[v] * (h[v] @ [Wmu | Wls]), stored fp16
__global__ __launch_bounds__(256) void k_gemm2(const float* __restrict__ h,
                                               const _Float16* __restrict__ wf2h,
                                               const _Float16* __restrict__ wf2l,
                                               const float* __restrict__ dis,
                                               _Float16* __restrict__ t2) {
    int tid = threadIdx.x;
    int lane = tid & 63;
    int wv = tid >> 6;
    int wrow = blockIdx.x * 64 + wv * 16;
    int cl = lane & 15, kg = lane >> 4;
    const half8v* Bh = (const half8v*)wf2h;
    const half8v* Bl = (const half8v*)wf2l;
    float4v acc[4] = {};
    int r = wrow + cl;
    long rr = (r < NN) ? r : (NN - 1);
    const float4* hp = (const float4*)(h + rr * 64);
#pragma unroll
    for (int kc = 0; kc < 2; ++kc) {
        float4 xa = hp[kc * 8 + kg * 2];
        float4 xb = hp[kc * 8 + kg * 2 + 1];
        half8v ah, al;
        split8(xa, xb, ah, al);
#pragma unroll
        for (int ct = 0; ct < 4; ++ct) {
            half8v bh = Bh[(ct * 2 + kc) * 64 + lane];
            half8v bl = Bl[(ct * 2 + kc) * 64 + lane];
            acc[ct] = __builtin_amdgcn_mfma_f32_16x16x32_f16(ah, bh, acc[ct], 0, 0, 0);
            acc[ct] = __builtin_amdgcn_mfma_f32_16x16x32_f16(al, bh, acc[ct], 0, 0, 0);
            acc[ct] = __builtin_amdgcn_mfma_f32_16x16x32_f16(ah, bl, acc[ct], 0, 0, 0);
        }
    }
#pragma unroll
    for (int j = 0; j < 4; ++j) {
        int row = wrow + kg * 4 + j;
        if (row < NN) {
            float dv = dis[row];
#pragma unroll
            for (int ct = 0; ct < 4; ++ct)
                t2[(long)row * 64 + ct * 16 + cl] = (_Float16)(acc[ct][j] * dv);
        }
    }
}

// ---------------- fused gather-aggregations ----------------
// 16 lanes per node, 8 B (half4) per lane -> one wave-instruction gathers 4 rows' worth.
// 16-deep load batches for MLP; last batch masked via 0/1 fma weight with clamped
// duplicate-address loads (same line -> L1 hit, no extra L3 traffic, no serial tail).
// ds_swizzle BitMode (pattern must be a literal): lane' = (lane & 0x10) | K — broadcast
// lane K of the 16-lane node group; group exec mask is uniform so sources are active.

#define SWZ_LD(K) r[K] = t4[(__builtin_amdgcn_ds_swizzle(idx, ((K) << 5) | 0x10) << 4) + j4];

__device__ __forceinline__ void batch16_full(const half4v* __restrict__ t4, int idx,
                                             int j4, float* a) {
    half4v r[16];
    SWZ_LD(0)  SWZ_LD(1)  SWZ_LD(2)  SWZ_LD(3)
    SWZ_LD(4)  SWZ_LD(5)  SWZ_LD(6)  SWZ_LD(7)
    SWZ_LD(8)  SWZ_LD(9)  SWZ_LD(10) SWZ_LD(11)
    SWZ_LD(12) SWZ_LD(13) SWZ_LD(14) SWZ_LD(15)
#pragma unroll
    for (int k = 0; k < 16; ++k) {
        a[0] += (float)r[k][0]; a[1] += (float)r[k][1];
        a[2] += (float)r[k][2]; a[3] += (float)r[k][3];
    }
}

__device__ __forceinline__ void batch16_mask(const half4v* __restrict__ t4, int idx,
                                             int j4, int cnt, float* a) {
    half4v r[16];
    SWZ_LD(0)  SWZ_LD(1)  SWZ_LD(2)  SWZ_LD(3)
    SWZ_LD(4)  SWZ_LD(5)  SWZ_LD(6)  SWZ_LD(7)
    SWZ_LD(8)  SWZ_LD(9)  SWZ_LD(10) SWZ_LD(11)
    SWZ_LD(12) SWZ_LD(13) SWZ_LD(14) SWZ_LD(15)
#pragma unroll
    for (int k = 0; k < 16; ++k) {
        float w = (k < cnt) ? 1.0f : 0.0f;
        a[0] += w * (float)r[k][0]; a[1] += w * (float)r[k][1];
        a[2] += w * (float)r[k][2]; a[3] += w * (float)r[k][3];
    }
}

__device__ __forceinline__ void batch8_mask(const half4v* __restrict__ t4, int idx,
                                            int j4, int cnt, float* a) {
    half4v r[8];
    SWZ_LD(0)  SWZ_LD(1)  SWZ_LD(2)  SWZ_LD(3)
    SWZ_LD(4)  SWZ_LD(5)  SWZ_LD(6)  SWZ_LD(7)
#pragma unroll
    for (int k = 0; k < 8; ++k) {
        float w = (k < cnt) ? 1.0f : 0.0f;
        a[0] += w * (float)r[k][0]; a[1] += w * (float)r[k][1];
        a[2] += w * (float)r[k][2]; a[3] += w * (float)r[k][3];
    }
}

// h[v] = l2normalize(relu(dis[v]*(sum_s t1'[s] + t1'[v]) + b1))
__global__ __launch_bounds__(256) void k_agg1(const half4v* __restrict__ tv4,
                                              const int* __restrict__ row_ptr,
                                              const int* __restrict__ csr_src,
                                              const float* __restrict__ dis,
                                              const float* __restrict__ b1,
                                              float* __restrict__ h) {
    int lane = threadIdx.x & 63;
    int j4 = lane & 15;
    int v = blockIdx.x * 16 + (threadIdx.x >> 6) * 4 + (lane >> 4);  // NN = 6250*16
    int beg = row_ptr[v], end = row_ptr[v + 1];
    float a[4] = {0.f, 0.f, 0.f, 0.f};
    int base = beg;
    for (; base + 16 <= end; base += 16) {
        int idx = csr_src[base + j4];
        batch16_full(tv4, idx, j4, a);
    }
    int cnt = end - base;
    if (cnt > 0) {
        int idx = csr_src[base + ((j4 < cnt) ? j4 : cnt - 1)];
        if (cnt > 8) batch16_mask(tv4, idx, j4, cnt, a);
        else         batch8_mask(tv4, idx, j4, cnt, a);
    }
    float dv = dis[v];
    half4v rv = tv4[(v << 4) + j4];              // = dis[v]*t1[v]
    float4 bb = ((const float4*)b1)[j4];
    float val0 = fmaxf(dv * (a[0] + (float)rv[0]) + bb.x, 0.0f);
    float val1 = fmaxf(dv * (a[1] + (float)rv[1]) + bb.y, 0.0f);
    float val2 = fmaxf(dv * (a[2] + (float)rv[2]) + bb.z, 0.0f);
    float val3 = fmaxf(dv * (a[3] + (float)rv[3]) + bb.w, 0.0f);
    float ss = val0 * val0 + val1 * val1 + val2 * val2 + val3 * val3;
#pragma unroll
    for (int m = 1; m < 16; m <<= 1) ss += __shfl_xor(ss, m);
    float scale = 1.0f / fmaxf(sqrtf(ss), 1e-12f);
    float4v* h4 = (float4v*)h;
    float4v hv; hv.x = val0 * scale; hv.y = val1 * scale;
    hv.z = val2 * scale; hv.w = val3 * scale;
    h4[(v << 4) + j4] = hv;
}

// layer-2 aggregation fused with bias + reparametrize; writes mu, ls (f32), z (fp16)
__global__ __launch_bounds__(256) void k_agg2(const half4v* __restrict__ tv4,
                                              const int* __restrict__ row_ptr,
                                              const int* __restrict__ csr_src,
                                              const float* __restrict__ dis,
                                              const float* __restrict__ bmu,
                                              const float* __restrict__ bls,
                                              const float* __restrict__ eps,
                                              float* __restrict__ mu,
                                              float* __restrict__ ls,
                                              _Float16* __restrict__ zh) {
    int lane = threadIdx.x & 63;
    int j4 = lane & 15;
    int v = blockIdx.x * 16 + (threadIdx.x >> 6) * 4 + (lane >> 4);
    int beg = row_ptr[v], end = row_ptr[v + 1];
    float a[4] = {0.f, 0.f, 0.f, 0.f};
    int base = beg;
    for (; base + 16 <= end; base += 16) {
        int idx = csr_src[base + j4];
        batch16_full(tv4, idx, j4, a);
    }
    int cnt = end - base;
    if (cnt > 0) {
        int idx = csr_src[base + ((j4 < cnt) ? j4 : cnt - 1)];
        if (cnt > 8) batch16_mask(tv4, idx, j4, cnt, a);
        else         batch8_mask(tv4, idx, j4, cnt, a);
    }
    float dv = dis[v];
    half4v rv = tv4[(v << 4) + j4];              // = dis[v]*t2[v]
    float4 bb = (j4 < 8) ? ((const float4*)bmu)[j4] : ((const float4*)bls)[j4 - 8];
    float val0 = dv * (a[0] + (float)rv[0]) + bb.x;
    float val1 = dv * (a[1] + (float)rv[1]) + bb.y;
    float val2 = dv * (a[2] + (float)rv[2]) + bb.z;
    float val3 = dv * (a[3] + (float)rv[3]) + bb.w;
    // partner lane (j4^8) holds the logstd (resp. mu) for the same dims
    float o0 = __shfl_xor(val0, 8);
    float o1 = __shfl_xor(val1, 8);
    float o2 = __shfl_xor(val2, 8);
    float o3 = __shfl_xor(val3, 8);
    float4v* mu4 = (float4v*)mu;
    float4v* ls4 = (float4v*)ls;
    half4v* z4  = (half4v*)zh;
    const float4* e4 = (const float4*)eps;
    if (j4 < 8) {
        float4v mv; mv.x = val0; mv.y = val1; mv.z = val2; mv.w = val3;
        __builtin_nontemporal_store(mv, &mu4[(v << 3) + j4]);
        float4 ev = e4[(v << 3) + j4];
        float l0 = fminf(fmaxf(o0, -10.0f), 10.0f);
        float l1 = fminf(fmaxf(o1, -10.0f), 10.0f);
        float l2 = fminf(fmaxf(o2, -10.0f), 10.0f);
        float l3 = fminf(fmaxf(o3, -10.0f), 10.0f);
        half4v zw;
        zw[0] = (_Float16)(val0 + ev.x * expf(l0));
        zw[1] = (_Float16)(val1 + ev.y * expf(l1));
        zw[2] = (_Float16)(val2 + ev.z * expf(l2));
        zw[3] = (_Float16)(val3 + ev.w * expf(l3));
        z4[(v << 3) + j4] = zw;
    } else {
        float4v lv; lv.x = val0; lv.y = val1; lv.z = val2; lv.w = val3;
        __builtin_nontemporal_store(lv, &ls4[(v << 3) + (j4 - 8)]);
    }
}

// adj_pred[e] = sigmoid(<z[src], z[dst]>); z fp16 (row = 64 B = 1 line),
// 4 lanes per edge, 16 B loads
__global__ __launch_bounds__(256) void k_decode(const _Float16* __restrict__ zh,
                                                const int* __restrict__ src,
                                                const int* __restrict__ dst,
                                                float* __restrict__ out) {
    long t = (long)blockIdx.x * 256 + threadIdx.x;
    long e = t >> 2; int l = (int)(t & 3);
    if (e >= NE) return;
    int s = src[e], d = dst[e];
    const half8v* z8 = (const half8v*)zh;
    half8v a = z8[s * 4 + l];
    half8v b = z8[d * 4 + l];
    float p = 0.f;
#pragma unroll
    for (int i = 0; i < 8; ++i) p += (float)a[i] * (float)b[i];
    p += __shfl_xor(p, 1);
    p += __shfl_xor(p, 2);
    if (l == 0) out[e] = 1.0f / (1.0f + expf(-p));
}

extern "C" void kernel_launch(void* const* d_in, const int* in_sizes, int n_in,
                              void* d_out, int out_size, void* d_ws, size_t ws_size,
                              hipStream_t stream) {
    const float* x   = (const float*)d_in[0];
    const int*   ei  = (const int*)d_in[1];
    const float* eps = (const float*)d_in[2];
    const float* W1  = (const float*)d_in[3];
    const float* b1  = (const float*)d_in[4];
    const float* Wmu = (const float*)d_in[5];
    const float* bmu = (const float*)d_in[6];
    const float* Wls = (const float*)d_in[7];
    const float* bls = (const float*)d_in[8];
    const int* src = ei;        // edge_index[0]
    const int* dst = ei + NE;   // edge_index[1]

    float* out = (float*)d_out;
    float* adj = out;                       // [E]
    float* mu  = out + NE;                  // [N,32]
    float* ls  = mu + (long)NN * 32;        // [N,32]

    // workspace layout (all block byte sizes multiples of 16; z 64B-aligned)
    float* dis      = (float*)d_ws;              // NN
    int*   row_ptr  = (int*)(dis + NN);          // 100004
    int*   bucket_base = row_ptr + 100004;       // NB_BKT+1 -> pad 784
    int*   counts   = bucket_base + 784;         // NT*NB_BKT = 76636 -> pad 76640
    int*   ebuf     = counts + 76640;            // NE
    int*   csr_src  = ebuf + NE;                 // NE
    _Float16* t     = (_Float16*)(csr_src + NE); // NN*64 fp16 (t1' then t2')
    float* h        = (float*)(t + (long)NN * 64);         // NN*64 f32
    _Float16* zh    = (_Float16*)(h + (long)NN * 64 + 12); // NN*32 fp16, 64B-aligned

    // W fragment tables alias the counts region (dead after k_place; k_wprep is
    // stream-ordered after k_place). 49152 B << 306 KB region, 16B-aligned.
    _Float16* wf1h = (_Float16*)counts;          // 16x64x8 = 8192 f16
    _Float16* wf1l = wf1h + 8192;                // 8192
    _Float16* wf2h = wf1l + 8192;                // 8x64x8 = 4096
    _Float16* wf2l = wf2h + 4096;                // 4096

    const int B = 256;

    // CSR + deg/dis build — zero global atomics
    k_cnt  <<<NT, B, 0, stream>>>(dst, counts);
    k_bscan<<<1, 1024, 0, stream>>>(counts, bucket_base);
    k_offs <<<(NB_BKT + B - 1) / B, B, 0, stream>>>(bucket_base, counts);
    k_place<<<NT, B, 0, stream>>>(src, dst, counts, ebuf);
    k_wprep<<<1, B, 0, stream>>>(W1, Wmu, Wls, wf1h, wf1l, wf2h, wf2l);
    k_build<<<NB_BKT, B, 0, stream>>>(bucket_base, ebuf, csr_src, row_ptr, dis);

    // layer 1
    k_gemm1<<<(NN + 63) / 64, B, 0, stream>>>(x, wf1h, wf1l, dis, t);
    k_agg1 <<<NN / 16, B, 0, stream>>>((const half4v*)t, row_ptr, csr_src, dis, b1, h);

    // layer 2
    k_gemm2<<<(NN + 63) / 64, B, 0, stream>>>(h, wf2h, wf2l, dis, t);
    k_agg2 <<<NN / 16, B, 0, stream>>>((const half4v*)t, row_ptr, csr_src, dis,
                                       bmu, bls, eps, mu, ls, zh);

    // decode
    k_decode<<<(int)(((long)NE * 4 + B - 1) / B), B, 0, stream>>>(zh, src, dst, adj);
}